// Round 10
// baseline (308.068 us; speedup 1.0000x reference)
//
#include <hip/hip_runtime.h>
#include <hip/hip_bf16.h>

// ---------------------------------------------------------------------------
// GCN 4-layer forward on MI355X.
//   - R6: single-pass SLOTTED CSR build (one device atomic per (bin,tile)).
//   - R6: k_w4 fused into agg3 (h3 never materialized).
//   - R5: float4 gathers (D/4 lanes/node), agg epilogue fusion.
//   - R7: k_agg 8-edge unroll.
//   - R8 lesson: LDS reads must be dense float4 @ 16B*tid stride (0 conflicts);
//     32B-stride column reads = 4-way conflict (2.8M SQ_LDS_BANK_CONFLICT).
//   - R10: GEMM 4x8 microtile with SPLIT column reads (w_lo @ tx*4, w_hi @
//     M/2 + tx*4) — both dense-16B patterns => conflict-free, 0.75 B/FLOP
//     (vs 1.0 for 4x4). LDS <= 50KB keeps 3 blocks/CU. L1/L2 only; L3 = 4x4.
//   - pool: wave segmented scan on sorted gid (R1: contended atomics 152us).
// ---------------------------------------------------------------------------

#define TILE 4096   // edges per build tile (256 threads x 16)
#define SLOT 8192   // per-bin slot capacity (bin = 512 nodes, mean ~4080 edges)

// --- build pass 1: tile->LDS, histogram, reserve slot space, scatter -------
__global__ __launch_bounds__(256) void k_buildbins(
        const int* __restrict__ src, const int* __restrict__ dst, int E, int NBIN,
        int* __restrict__ cntD, int* __restrict__ cntS,
        int* __restrict__ bucketD, unsigned short* __restrict__ bucketS) {
    __shared__ int ssrc[TILE];
    __shared__ int sdst[TILE];
    __shared__ int hD[256], hS[256], bD[256], bS[256];
    int t = threadIdx.x;
    hD[t] = 0; hS[t] = 0;
    __syncthreads();
    int base = blockIdx.x * TILE;
    int lim = min(TILE, E - base);
#pragma unroll
    for (int k = 0; k < TILE / 256; k++) {
        int i = k * 256 + t;
        if (i < lim) {
            int d = dst[base + i], sv = src[base + i];
            sdst[i] = d; ssrc[i] = sv;
            atomicAdd(&hD[d >> 9], 1);
            atomicAdd(&hS[sv >> 9], 1);
        }
    }
    __syncthreads();
    if (t < NBIN) {
        bD[t] = (hD[t] > 0) ? atomicAdd(&cntD[t], hD[t]) : 0;
        bS[t] = (hS[t] > 0) ? atomicAdd(&cntS[t], hS[t]) : 0;
        hD[t] = 0; hS[t] = 0;
    }
    __syncthreads();
#pragma unroll
    for (int k = 0; k < TILE / 256; k++) {
        int i = k * 256 + t;
        if (i < lim) {
            int d = sdst[i], sv = ssrc[i];
            int binD = d >> 9, binS = sv >> 9;
            int pD = atomicAdd(&hD[binD], 1) + bD[binD];
            bucketD[binD * SLOT + pD] = (sv << 9) | (d & 511);
            int pS = atomicAdd(&hS[binS], 1) + bS[binS];
            bucketS[binS * SLOT + pS] = (unsigned short)(sv & 511);
        }
    }
}

// --- build pass 2: per-src-bucket LDS count -> norm_out --------------------
__global__ __launch_bounds__(256) void k_degout(const unsigned short* __restrict__ bucketS,
                                                const int* __restrict__ cntS,
                                                int N, float* __restrict__ norm_out) {
    __shared__ int cnt[512];
    int t = threadIdx.x;
    cnt[t] = 0; cnt[t + 256] = 0;
    __syncthreads();
    int bin = blockIdx.x;
    int b0 = bin * SLOT, cn = cntS[bin];
    for (int j = t; j < cn; j += 256) atomicAdd(&cnt[bucketS[b0 + j]], 1);
    __syncthreads();
    int base = bin << 9;
    for (int l = t; l < 512; l += 256) {
        int g = base + l;
        if (g < N) norm_out[g] = rsqrtf(fmaxf((float)cnt[l], 1.0f));
    }
}

// --- build pass 3: per-dst-bucket count+scan -> rowBE/norm_in, place edges -
__global__ __launch_bounds__(256) void k_build(const int* __restrict__ bucketD,
                                               const int* __restrict__ cntDg,
                                               const float* __restrict__ norm_out,
                                               int N, int2* __restrict__ rowBE,
                                               float* __restrict__ norm_in,
                                               int2* __restrict__ edges) {
    __shared__ int cnt[512], sc[512];
    int t = threadIdx.x;
    cnt[t] = 0; cnt[t + 256] = 0;
    __syncthreads();
    int bin = blockIdx.x;
    int b0 = bin * SLOT, cn = cntDg[bin];
    for (int j = t; j < cn; j += 256) atomicAdd(&cnt[bucketD[b0 + j] & 511], 1);
    __syncthreads();
    sc[t] = cnt[t]; sc[t + 256] = cnt[t + 256];
    __syncthreads();
    for (int off = 1; off < 512; off <<= 1) {
        int v0 = (t >= off) ? sc[t - off] : 0;
        int i1 = t + 256;
        int v1 = sc[i1 - off];   // i1 >= 256 >= off always
        __syncthreads();
        sc[t] += v0; sc[i1] += v1;
        __syncthreads();
    }
    int base = bin << 9;
    for (int l = t; l < 512; l += 256) {
        int g = base + l;
        int e = sc[l] - cnt[l];          // exclusive within bucket
        if (g < N) {
            rowBE[g] = make_int2(b0 + e, b0 + sc[l]);
            norm_in[g] = rsqrtf(fmaxf((float)cnt[l], 1.0f));
        }
        cnt[l] = e;                      // becomes placement cursor
    }
    __syncthreads();
    for (int j = t; j < cn; j += 256) {
        int p = bucketD[b0 + j];
        int sv = p >> 9, dl = p & 511;
        int pos = atomicAdd(&cnt[dl], 1);
        edges[b0 + pos] = make_int2(sv, __float_as_int(norm_out[sv]));
    }
}

// gather aggregation, float4 lanes: G = D/4 lanes per node, 8-edge unroll.
// EPI: out = relu(acc * norm[node] + bias4[lane])
template <int D, bool EPI>
__global__ __launch_bounds__(256) void k_agg(const float4* __restrict__ h4,
                                             const int2* __restrict__ edges,
                                             const int2* __restrict__ rowBE, int n,
                                             float4* __restrict__ out4,
                                             const float* __restrict__ norm,
                                             const float4* __restrict__ bias4) {
    constexpr int G = D / 4;           // lanes per node
    const int per = 256 / G;           // nodes per block
    int node = blockIdx.x * per + threadIdx.x / G;
    int lane = threadIdx.x % G;
    if (node >= n) return;
    int2 be = rowBE[node];
    int j = be.x, end = be.y;
    float4 acc = make_float4(0.f, 0.f, 0.f, 0.f);
    for (; j + 7 < end; j += 8) {
        int2 e[8];
        float4 v[8];
#pragma unroll
        for (int q = 0; q < 8; q++) e[q] = edges[j + q];
#pragma unroll
        for (int q = 0; q < 8; q++) v[q] = h4[(size_t)e[q].x * G + lane];
#pragma unroll
        for (int q = 0; q < 8; q++) {
            float wq = __int_as_float(e[q].y);
            acc.x += v[q].x * wq;
            acc.y += v[q].y * wq;
            acc.z += v[q].z * wq;
            acc.w += v[q].w * wq;
        }
    }
    if (j + 3 < end) {
        int2 e0 = edges[j];
        int2 e1 = edges[j + 1];
        int2 e2 = edges[j + 2];
        int2 e3 = edges[j + 3];
        float4 v0 = h4[(size_t)e0.x * G + lane];
        float4 v1 = h4[(size_t)e1.x * G + lane];
        float4 v2 = h4[(size_t)e2.x * G + lane];
        float4 v3 = h4[(size_t)e3.x * G + lane];
        float w0 = __int_as_float(e0.y), w1 = __int_as_float(e1.y);
        float w2 = __int_as_float(e2.y), w3 = __int_as_float(e3.y);
        acc.x += v0.x * w0 + v1.x * w1 + v2.x * w2 + v3.x * w3;
        acc.y += v0.y * w0 + v1.y * w1 + v2.y * w2 + v3.y * w3;
        acc.z += v0.z * w0 + v1.z * w1 + v2.z * w2 + v3.z * w3;
        acc.w += v0.w * w0 + v1.w * w1 + v2.w * w2 + v3.w * w3;
        j += 4;
    }
    for (; j < end; j++) {
        int2 e = edges[j];
        float4 v = h4[(size_t)e.x * G + lane];
        float w0 = __int_as_float(e.y);
        acc.x += v.x * w0; acc.y += v.y * w0; acc.z += v.z * w0; acc.w += v.w * w0;
    }
    if (EPI) {
        float s = norm[node];
        float4 b = bias4[lane];
        acc.x = fmaxf(acc.x * s + b.x, 0.f);
        acc.y = fmaxf(acc.y * s + b.y, 0.f);
        acc.z = fmaxf(acc.z * s + b.z, 0.f);
        acc.w = fmaxf(acc.w * s + b.w, 0.f);
    }
    out4[(size_t)node * G + lane] = acc;
}

// agg3 + W4 fused (D=32): h3 = relu(agg(t3)*norm+b3) in regs (never stored),
// t4[node] = h3 @ W4 via per-lane partials + 8-lane __shfl_xor reduce.
__global__ __launch_bounds__(256) void k_aggw4(const float4* __restrict__ h4,
                        const int2* __restrict__ edges, const int2* __restrict__ rowBE,
                        const float* __restrict__ norm, const float4* __restrict__ b3_4,
                        const float* __restrict__ W4, int n, float4* __restrict__ t4) {
    __shared__ float w[128];
    if (threadIdx.x < 128) w[threadIdx.x] = W4[threadIdx.x];
    __syncthreads();
    int node = blockIdx.x * 32 + threadIdx.x / 8;
    int lane = threadIdx.x % 8;
    if (node >= n) return;
    float4 wr0 = ((const float4*)w)[4 * lane + 0];
    float4 wr1 = ((const float4*)w)[4 * lane + 1];
    float4 wr2 = ((const float4*)w)[4 * lane + 2];
    float4 wr3 = ((const float4*)w)[4 * lane + 3];
    int2 be = rowBE[node];
    int j = be.x, end = be.y;
    float4 acc = make_float4(0.f, 0.f, 0.f, 0.f);
    for (; j + 3 < end; j += 4) {
        int2 e0 = edges[j];
        int2 e1 = edges[j + 1];
        int2 e2 = edges[j + 2];
        int2 e3 = edges[j + 3];
        float4 v0 = h4[(size_t)e0.x * 8 + lane];
        float4 v1 = h4[(size_t)e1.x * 8 + lane];
        float4 v2 = h4[(size_t)e2.x * 8 + lane];
        float4 v3 = h4[(size_t)e3.x * 8 + lane];
        float w0 = __int_as_float(e0.y), w1 = __int_as_float(e1.y);
        float w2 = __int_as_float(e2.y), w3 = __int_as_float(e3.y);
        acc.x += v0.x * w0 + v1.x * w1 + v2.x * w2 + v3.x * w3;
        acc.y += v0.y * w0 + v1.y * w1 + v2.y * w2 + v3.y * w3;
        acc.z += v0.z * w0 + v1.z * w1 + v2.z * w2 + v3.z * w3;
        acc.w += v0.w * w0 + v1.w * w1 + v2.w * w2 + v3.w * w3;
    }
    for (; j < end; j++) {
        int2 e = edges[j];
        float4 v = h4[(size_t)e.x * 8 + lane];
        float w0 = __int_as_float(e.y);
        acc.x += v.x * w0; acc.y += v.y * w0; acc.z += v.z * w0; acc.w += v.w * w0;
    }
    float s = norm[node];
    float4 b = b3_4[lane];
    float hx = fmaxf(acc.x * s + b.x, 0.f);
    float hy = fmaxf(acc.y * s + b.y, 0.f);
    float hz = fmaxf(acc.z * s + b.z, 0.f);
    float hw = fmaxf(acc.w * s + b.w, 0.f);
    float4 p;
    p.x = hx * wr0.x + hy * wr1.x + hz * wr2.x + hw * wr3.x;
    p.y = hx * wr0.y + hy * wr1.y + hz * wr2.y + hw * wr3.y;
    p.z = hx * wr0.z + hy * wr1.z + hz * wr2.z + hw * wr3.z;
    p.w = hx * wr0.w + hy * wr1.w + hz * wr2.w + hw * wr3.w;
#pragma unroll
    for (int m = 1; m < 8; m <<= 1) {
        p.x += __shfl_xor(p.x, m);
        p.y += __shfl_xor(p.y, m);
        p.z += __shfl_xor(p.z, m);
        p.w += __shfl_xor(p.w, m);
    }
    if (lane == 0) t4[node] = p;
}

// out[N x M] = op(A[N x K] (opt row-scaled)) @ W[K x M] (+bias, relu).
// 4 rows x 8 cols per thread, cols SPLIT as [tx*4, tx*4+4) and [M/2+tx*4, ..):
// both w reads are dense float4 @ 16B*tx stride (R8 lesson: conflict-free),
// 0.75 B/FLOP vs 1.0 for 4x4.
template <int K, int M, bool PRESCALE, bool BIAS_RELU>
__global__ __launch_bounds__(256) void k_gemm8(const float* __restrict__ A,
                                               const float* __restrict__ W,
                                               const float* __restrict__ bias,
                                               const float* __restrict__ norm, int N,
                                               float* __restrict__ out) {
    constexpr int CT   = M / 8;        // col threads (each does 2x float4 cols)
    constexpr int RTH  = 256 / CT;     // row threads
    constexpr int ROWS = RTH * 4;      // rows per block
    constexpr int KC   = (K > 64) ? 64 : K;
    constexpr int APAD = ROWS + 4;
    constexpr int HM   = M / 2;
    __shared__ float Alds[KC * APAD];  // transposed: Alds[k][r]
    __shared__ float Wlds[KC * M];
    int t  = threadIdx.x;
    int tx = t % CT;
    int ty = t / CT;
    int row0 = blockIdx.x * ROWS;
    float accL[4][4] = {};
    float accH[4][4] = {};
    for (int kc = 0; kc < K; kc += KC) {
        for (int idx = t; idx < KC * M / 4; idx += 256)
            ((float4*)Wlds)[idx] = ((const float4*)(W + kc * M))[idx];
        constexpr int A4 = ROWS * KC / 4;
        for (int idx = t; idx < A4; idx += 256) {
            int r  = idx / (KC / 4);
            int k4 = idx % (KC / 4);
            int grow = row0 + r;
            float4 v = make_float4(0.f, 0.f, 0.f, 0.f);
            if (grow < N) {
                v = *(const float4*)(A + (size_t)grow * K + kc + k4 * 4);
                if (PRESCALE) {
                    float s = norm[grow];
                    v.x *= s; v.y *= s; v.z *= s; v.w *= s;
                }
            }
            Alds[(k4 * 4 + 0) * APAD + r] = v.x;
            Alds[(k4 * 4 + 1) * APAD + r] = v.y;
            Alds[(k4 * 4 + 2) * APAD + r] = v.z;
            Alds[(k4 * 4 + 3) * APAD + r] = v.w;
        }
        __syncthreads();
#pragma unroll 4
        for (int k = 0; k < KC; k++) {
            float4 a  = *(const float4*)&Alds[k * APAD + ty * 4];
            float4 wl = *(const float4*)&Wlds[k * M + tx * 4];
            float4 wh = *(const float4*)&Wlds[k * M + HM + tx * 4];
            accL[0][0] += a.x * wl.x; accL[0][1] += a.x * wl.y; accL[0][2] += a.x * wl.z; accL[0][3] += a.x * wl.w;
            accL[1][0] += a.y * wl.x; accL[1][1] += a.y * wl.y; accL[1][2] += a.y * wl.z; accL[1][3] += a.y * wl.w;
            accL[2][0] += a.z * wl.x; accL[2][1] += a.z * wl.y; accL[2][2] += a.z * wl.z; accL[2][3] += a.z * wl.w;
            accL[3][0] += a.w * wl.x; accL[3][1] += a.w * wl.y; accL[3][2] += a.w * wl.z; accL[3][3] += a.w * wl.w;
            accH[0][0] += a.x * wh.x; accH[0][1] += a.x * wh.y; accH[0][2] += a.x * wh.z; accH[0][3] += a.x * wh.w;
            accH[1][0] += a.y * wh.x; accH[1][1] += a.y * wh.y; accH[1][2] += a.y * wh.z; accH[1][3] += a.y * wh.w;
            accH[2][0] += a.z * wh.x; accH[2][1] += a.z * wh.y; accH[2][2] += a.z * wh.z; accH[2][3] += a.z * wh.w;
            accH[3][0] += a.w * wh.x; accH[3][1] += a.w * wh.y; accH[3][2] += a.w * wh.z; accH[3][3] += a.w * wh.w;
        }
        __syncthreads();
    }
#pragma unroll
    for (int i = 0; i < 4; i++) {
        int grow = row0 + ty * 4 + i;
        if (grow < N) {
            float4 oL = make_float4(accL[i][0], accL[i][1], accL[i][2], accL[i][3]);
            float4 oH = make_float4(accH[i][0], accH[i][1], accH[i][2], accH[i][3]);
            if (BIAS_RELU) {
                float4 bL = *(const float4*)(bias + tx * 4);
                float4 bH = *(const float4*)(bias + HM + tx * 4);
                oL.x = fmaxf(oL.x + bL.x, 0.f); oL.y = fmaxf(oL.y + bL.y, 0.f);
                oL.z = fmaxf(oL.z + bL.z, 0.f); oL.w = fmaxf(oL.w + bL.w, 0.f);
                oH.x = fmaxf(oH.x + bH.x, 0.f); oH.y = fmaxf(oH.y + bH.y, 0.f);
                oH.z = fmaxf(oH.z + bH.z, 0.f); oH.w = fmaxf(oH.w + bH.w, 0.f);
            }
            *(float4*)(out + (size_t)grow * M + tx * 4) = oL;
            *(float4*)(out + (size_t)grow * M + HM + tx * 4) = oH;
        }
    }
}

// R6-proven 4x4 microtile (kept for the small L3 GEMM)
template <int K, int M, bool PRESCALE, bool BIAS_RELU>
__global__ __launch_bounds__(256) void k_gemm(const float* __restrict__ A,
                                              const float* __restrict__ W,
                                              const float* __restrict__ bias,
                                              const float* __restrict__ norm, int N,
                                              float* __restrict__ out) {
    constexpr int CT   = M / 4;
    constexpr int RTH  = 256 / CT;
    constexpr int ROWS = RTH * 4;
    constexpr int KC   = (K > 64) ? 64 : K;
    constexpr int APAD = ROWS + 4;
    __shared__ float Alds[KC * APAD];
    __shared__ float Wlds[KC * M];
    int t  = threadIdx.x;
    int tx = t % CT;
    int ty = t / CT;
    int row0 = blockIdx.x * ROWS;
    float acc[4][4] = {};
    for (int kc = 0; kc < K; kc += KC) {
        for (int idx = t; idx < KC * M / 4; idx += 256)
            ((float4*)Wlds)[idx] = ((const float4*)(W + kc * M))[idx];
        constexpr int A4 = ROWS * KC / 4;
        for (int idx = t; idx < A4; idx += 256) {
            int r  = idx / (KC / 4);
            int k4 = idx % (KC / 4);
            int grow = row0 + r;
            float4 v = make_float4(0.f, 0.f, 0.f, 0.f);
            if (grow < N) {
                v = *(const float4*)(A + (size_t)grow * K + kc + k4 * 4);
                if (PRESCALE) {
                    float s = norm[grow];
                    v.x *= s; v.y *= s; v.z *= s; v.w *= s;
                }
            }
            Alds[(k4 * 4 + 0) * APAD + r] = v.x;
            Alds[(k4 * 4 + 1) * APAD + r] = v.y;
            Alds[(k4 * 4 + 2) * APAD + r] = v.z;
            Alds[(k4 * 4 + 3) * APAD + r] = v.w;
        }
        __syncthreads();
#pragma unroll 8
        for (int k = 0; k < KC; k++) {
            float4 a = *(const float4*)&Alds[k * APAD + ty * 4];
            float4 w = *(const float4*)&Wlds[k * M + tx * 4];
            acc[0][0] += a.x * w.x; acc[0][1] += a.x * w.y; acc[0][2] += a.x * w.z; acc[0][3] += a.x * w.w;
            acc[1][0] += a.y * w.x; acc[1][1] += a.y * w.y; acc[1][2] += a.y * w.z; acc[1][3] += a.y * w.w;
            acc[2][0] += a.z * w.x; acc[2][1] += a.z * w.y; acc[2][2] += a.z * w.z; acc[2][3] += a.z * w.w;
            acc[3][0] += a.w * w.x; acc[3][1] += a.w * w.y; acc[3][2] += a.w * w.z; acc[3][3] += a.w * w.w;
        }
        __syncthreads();
    }
#pragma unroll
    for (int i = 0; i < 4; i++) {
        int grow = row0 + ty * 4 + i;
        if (grow < N) {
            float4 o = make_float4(acc[i][0], acc[i][1], acc[i][2], acc[i][3]);
            if (BIAS_RELU) {
                float4 b = *(const float4*)(bias + tx * 4);
                o.x = fmaxf(o.x + b.x, 0.f);
                o.y = fmaxf(o.y + b.y, 0.f);
                o.z = fmaxf(o.z + b.z, 0.f);
                o.w = fmaxf(o.w + b.w, 0.f);
            }
            *(float4*)(out + (size_t)grow * M + tx * 4) = o;
        }
    }
}

// L4 fused: per node (1 thread): acc = sum_e t4[src_e]*norm_out_e ;
// v = acc*norm_in + b4 ; wave segmented-scan pool on sorted gid -> atomics
__global__ __launch_bounds__(256) void k_aggpool(const float4* __restrict__ t4,
                        const int2* __restrict__ edges, const int2* __restrict__ rowBE,
                        const float* __restrict__ norm, const float* __restrict__ b4,
                        const int* __restrict__ gid, int N,
                        float* __restrict__ sums, float* __restrict__ counts) {
    int n = blockIdx.x * blockDim.x + threadIdx.x;
    int lane = threadIdx.x & 63;
    bool valid = (n < N);
    float v0 = 0.f, v1 = 0.f, v2 = 0.f, v3 = 0.f, cnt = 0.f;
    int g = -1;
    if (valid) {
        g = gid[n];
        int2 be = rowBE[n];
        int j = be.x, end = be.y;
        float4 acc = make_float4(0.f, 0.f, 0.f, 0.f);
        for (; j + 3 < end; j += 4) {
            int2 e0 = edges[j];
            int2 e1 = edges[j + 1];
            int2 e2 = edges[j + 2];
            int2 e3 = edges[j + 3];
            float4 x0 = t4[e0.x];
            float4 x1 = t4[e1.x];
            float4 x2 = t4[e2.x];
            float4 x3 = t4[e3.x];
            float w0 = __int_as_float(e0.y), w1 = __int_as_float(e1.y);
            float w2 = __int_as_float(e2.y), w3 = __int_as_float(e3.y);
            acc.x += x0.x * w0 + x1.x * w1 + x2.x * w2 + x3.x * w3;
            acc.y += x0.y * w0 + x1.y * w1 + x2.y * w2 + x3.y * w3;
            acc.z += x0.z * w0 + x1.z * w1 + x2.z * w2 + x3.z * w3;
            acc.w += x0.w * w0 + x1.w * w1 + x2.w * w2 + x3.w * w3;
        }
        for (; j < end; j++) {
            int2 e = edges[j];
            float4 x = t4[e.x];
            float w0 = __int_as_float(e.y);
            acc.x += x.x * w0; acc.y += x.y * w0; acc.z += x.z * w0; acc.w += x.w * w0;
        }
        float s = norm[n];
        v0 = acc.x * s + b4[0];
        v1 = acc.y * s + b4[1];
        v2 = acc.z * s + b4[2];
        v3 = acc.w * s + b4[3];
        cnt = 1.f;
    }
    // segmented inclusive scan across the 64-lane wave (gid sorted)
#pragma unroll
    for (int off = 1; off < 64; off <<= 1) {
        float u0 = __shfl_up(v0, off);
        float u1 = __shfl_up(v1, off);
        float u2 = __shfl_up(v2, off);
        float u3 = __shfl_up(v3, off);
        float uc = __shfl_up(cnt, off);
        int   ug = __shfl_up(g, off);
        if (lane >= off && ug == g) { v0 += u0; v1 += u1; v2 += u2; v3 += u3; cnt += uc; }
    }
    int gnext = __shfl_down(g, 1);
    bool boundary = (lane == 63) || (gnext != g);
    if (boundary && valid) {
        atomicAdd(&sums[g * 4 + 0], v0);
        atomicAdd(&sums[g * 4 + 1], v1);
        atomicAdd(&sums[g * 4 + 2], v2);
        atomicAdd(&sums[g * 4 + 3], v3);
        atomicAdd(&counts[g], cnt);
    }
}

__global__ void k_div(const float* __restrict__ sums, const float* __restrict__ counts,
                      int G, float* __restrict__ out) {
    int idx = blockIdx.x * blockDim.x + threadIdx.x;
    if (idx >= G * 4) return;
    out[idx] = sums[idx] / fmaxf(counts[idx >> 2], 1.0f);
}

extern "C" void kernel_launch(void* const* d_in, const int* in_sizes, int n_in,
                              void* d_out, int out_size, void* d_ws, size_t ws_size,
                              hipStream_t stream) {
    const float* x  = (const float*)d_in[0];
    const float* W1 = (const float*)d_in[1];
    const float* b1 = (const float*)d_in[2];
    const float* W2 = (const float*)d_in[3];
    const float* b2 = (const float*)d_in[4];
    const float* W3 = (const float*)d_in[5];
    const float* b3 = (const float*)d_in[6];
    const float* W4 = (const float*)d_in[7];
    const float* b4 = (const float*)d_in[8];
    const int* src = (const int*)d_in[9];
    const int* dst = (const int*)d_in[10];
    const int* gid = (const int*)d_in[11];

    const int N = in_sizes[0] / 64;
    const int E = in_sizes[9];
    const int G = out_size / 4;
    const int NP = ((N + 63) / 64) * 64;
    const int NBIN = (N + 511) >> 9;          // coarse bins (<=256 for N<=131072)
    const int T = (E + TILE - 1) / TILE;      // build tiles

    char* ws = (char*)d_ws;
    size_t off = 0;
    auto alloc = [&](size_t bytes) -> void* {
        void* p = (void*)(ws + off);
        off += (bytes + 255) & ~(size_t)255;
        return p;
    };
    // sums/counts/cntD/cntS contiguous (all sizes multiples of 256B) -> one memset
    float* sums     = (float*)alloc(2048 * 4);   // 500*4 used
    float* counts   = (float*)alloc(512 * 4);
    int*   cntD     = (int*)alloc(256 * 4);
    int*   cntS     = (int*)alloc(256 * 4);
    int*   bucketD  = (int*)alloc((size_t)NBIN * SLOT * 4);
    unsigned short* bucketS = (unsigned short*)alloc((size_t)NBIN * SLOT * 2);
    int2*  edges    = (int2*)alloc((size_t)NBIN * SLOT * 8);
    int2*  rowBE    = (int2*)alloc((size_t)NP * 8);
    float* norm_out = (float*)alloc((size_t)NP * 4);
    float* norm_in  = (float*)alloc((size_t)NP * 4);
    float* region0  = (float*)alloc((size_t)N * 128 * 4);  // h1
    float* region1  = (float*)alloc((size_t)N * 64 * 4);   // agg1 / t2 / t3
    float* region2  = (float*)alloc((size_t)N * 64 * 4);   // h2 / t4

    hipMemsetAsync(sums, 0, (2048 + 512 + 256 + 256) * 4, stream);

    // ---- slotted atomic-light CSR build (3 kernels) ----
    k_buildbins<<<T, 256, 0, stream>>>(src, dst, E, NBIN, cntD, cntS, bucketD, bucketS);
    k_degout<<<NBIN, 256, 0, stream>>>(bucketS, cntS, N, norm_out);
    k_build<<<NBIN, 256, 0, stream>>>(bucketD, cntD, norm_out, N, rowBE, norm_in, edges);

    int nb = (N + 255) / 256;
    // L1: agg(x) -> region1 ; h1 = relu((agg*norm_in)@W1+b1) -> region0
    k_agg<64, false><<<(N + 15) / 16, 256, 0, stream>>>((const float4*)x, edges, rowBE, N,
                                                        (float4*)region1, nullptr, nullptr);
    k_gemm8<64, 128, true, true><<<(N + 63) / 64, 256, 0, stream>>>(region1, W1, b1, norm_in, N, region0);
    // L2: t2 = h1@W2 -> region1 ; h2 = relu(agg(t2)*norm+b2) -> region2 (fused epi)
    k_gemm8<128, 64, false, false><<<(N + 127) / 128, 256, 0, stream>>>(region0, W2, nullptr, nullptr, N, region1);
    k_agg<64, true><<<(N + 15) / 16, 256, 0, stream>>>((const float4*)region1, edges, rowBE, N,
                                                       (float4*)region2, norm_in, (const float4*)b2);
    // L3: t3 = h2@W3 -> region1 ; t4 = relu(agg(t3)*norm+b3)@W4 -> region2 (h3 never stored)
    k_gemm<64, 32, false, false><<<(N + 127) / 128, 256, 0, stream>>>(region2, W3, nullptr, nullptr, N, region1);
    k_aggw4<<<(N + 31) / 32, 256, 0, stream>>>((const float4*)region1, edges, rowBE,
                                               norm_in, (const float4*)b3, W4, N,
                                               (float4*)region2);
    // L4: fused gather(t4)+norm+bias+pool
    k_aggpool<<<nb, 256, 0, stream>>>((const float4*)region2, edges, rowBE,
                                      norm_in, b4, gid, N, sums, counts);
    k_div<<<(G * 4 + 255) / 256, 256, 0, stream>>>(sums, counts, G, (float*)d_out);
}

// Round 11
// 307.537 us; speedup vs baseline: 1.0017x; 1.0017x over previous
//
#include <hip/hip_runtime.h>
#include <hip/hip_bf16.h>

// ---------------------------------------------------------------------------
// GCN 4-layer forward on MI355X.
//   - R6: single-pass SLOTTED CSR build (one device atomic per (bin,tile)).
//   - R6: k_w4 fused into agg3 (h3 never materialized).
//   - R5: float4 gathers (D/4 lanes/node), agg epilogue fusion.
//   - R7: k_agg 8-edge unroll.
//   - R10 finding: GEMM's 2.8M LDS conflicts were the A-TRANSPOSE STAGING
//     WRITES (stride APAD=ROWS+4 == 4 mod 32 -> 8 lanes/bank, 8-way), NOT the
//     inner-loop reads (R9 split-read had identical conflict count).
//   - R11 fix: no transpose. A staged as float4 Alds[k4*AP + r], AP=ROWS+1
//     (AP%8==1 -> staging b128 writes hit each bank exactly 2x/quarter-wave =
//     free). Inner loop: 4 row-float4s (broadcast across CT lanes) + 4 dense
//     w-float4s. 4x4 microtile (R8: proven shape).
//   - pool: wave segmented scan on sorted gid (R1: contended atomics 152us).
// ---------------------------------------------------------------------------

#define TILE 4096   // edges per build tile (256 threads x 16)
#define SLOT 8192   // per-bin slot capacity (bin = 512 nodes, mean ~4080 edges)

// --- build pass 1: tile->LDS, histogram, reserve slot space, scatter -------
__global__ __launch_bounds__(256) void k_buildbins(
        const int* __restrict__ src, const int* __restrict__ dst, int E, int NBIN,
        int* __restrict__ cntD, int* __restrict__ cntS,
        int* __restrict__ bucketD, unsigned short* __restrict__ bucketS) {
    __shared__ int ssrc[TILE];
    __shared__ int sdst[TILE];
    __shared__ int hD[256], hS[256], bD[256], bS[256];
    int t = threadIdx.x;
    hD[t] = 0; hS[t] = 0;
    __syncthreads();
    int base = blockIdx.x * TILE;
    int lim = min(TILE, E - base);
#pragma unroll
    for (int k = 0; k < TILE / 256; k++) {
        int i = k * 256 + t;
        if (i < lim) {
            int d = dst[base + i], sv = src[base + i];
            sdst[i] = d; ssrc[i] = sv;
            atomicAdd(&hD[d >> 9], 1);
            atomicAdd(&hS[sv >> 9], 1);
        }
    }
    __syncthreads();
    if (t < NBIN) {
        bD[t] = (hD[t] > 0) ? atomicAdd(&cntD[t], hD[t]) : 0;
        bS[t] = (hS[t] > 0) ? atomicAdd(&cntS[t], hS[t]) : 0;
        hD[t] = 0; hS[t] = 0;
    }
    __syncthreads();
#pragma unroll
    for (int k = 0; k < TILE / 256; k++) {
        int i = k * 256 + t;
        if (i < lim) {
            int d = sdst[i], sv = ssrc[i];
            int binD = d >> 9, binS = sv >> 9;
            int pD = atomicAdd(&hD[binD], 1) + bD[binD];
            bucketD[binD * SLOT + pD] = (sv << 9) | (d & 511);
            int pS = atomicAdd(&hS[binS], 1) + bS[binS];
            bucketS[binS * SLOT + pS] = (unsigned short)(sv & 511);
        }
    }
}

// --- build pass 2: per-src-bucket LDS count -> norm_out --------------------
__global__ __launch_bounds__(256) void k_degout(const unsigned short* __restrict__ bucketS,
                                                const int* __restrict__ cntS,
                                                int N, float* __restrict__ norm_out) {
    __shared__ int cnt[512];
    int t = threadIdx.x;
    cnt[t] = 0; cnt[t + 256] = 0;
    __syncthreads();
    int bin = blockIdx.x;
    int b0 = bin * SLOT, cn = cntS[bin];
    for (int j = t; j < cn; j += 256) atomicAdd(&cnt[bucketS[b0 + j]], 1);
    __syncthreads();
    int base = bin << 9;
    for (int l = t; l < 512; l += 256) {
        int g = base + l;
        if (g < N) norm_out[g] = rsqrtf(fmaxf((float)cnt[l], 1.0f));
    }
}

// --- build pass 3: per-dst-bucket count+scan -> rowBE/norm_in, place edges -
__global__ __launch_bounds__(256) void k_build(const int* __restrict__ bucketD,
                                               const int* __restrict__ cntDg,
                                               const float* __restrict__ norm_out,
                                               int N, int2* __restrict__ rowBE,
                                               float* __restrict__ norm_in,
                                               int2* __restrict__ edges) {
    __shared__ int cnt[512], sc[512];
    int t = threadIdx.x;
    cnt[t] = 0; cnt[t + 256] = 0;
    __syncthreads();
    int bin = blockIdx.x;
    int b0 = bin * SLOT, cn = cntDg[bin];
    for (int j = t; j < cn; j += 256) atomicAdd(&cnt[bucketD[b0 + j] & 511], 1);
    __syncthreads();
    sc[t] = cnt[t]; sc[t + 256] = cnt[t + 256];
    __syncthreads();
    for (int off = 1; off < 512; off <<= 1) {
        int v0 = (t >= off) ? sc[t - off] : 0;
        int i1 = t + 256;
        int v1 = sc[i1 - off];   // i1 >= 256 >= off always
        __syncthreads();
        sc[t] += v0; sc[i1] += v1;
        __syncthreads();
    }
    int base = bin << 9;
    for (int l = t; l < 512; l += 256) {
        int g = base + l;
        int e = sc[l] - cnt[l];          // exclusive within bucket
        if (g < N) {
            rowBE[g] = make_int2(b0 + e, b0 + sc[l]);
            norm_in[g] = rsqrtf(fmaxf((float)cnt[l], 1.0f));
        }
        cnt[l] = e;                      // becomes placement cursor
    }
    __syncthreads();
    for (int j = t; j < cn; j += 256) {
        int p = bucketD[b0 + j];
        int sv = p >> 9, dl = p & 511;
        int pos = atomicAdd(&cnt[dl], 1);
        edges[b0 + pos] = make_int2(sv, __float_as_int(norm_out[sv]));
    }
}

// gather aggregation, float4 lanes: G = D/4 lanes per node, 8-edge unroll.
// EPI: out = relu(acc * norm[node] + bias4[lane])
template <int D, bool EPI>
__global__ __launch_bounds__(256) void k_agg(const float4* __restrict__ h4,
                                             const int2* __restrict__ edges,
                                             const int2* __restrict__ rowBE, int n,
                                             float4* __restrict__ out4,
                                             const float* __restrict__ norm,
                                             const float4* __restrict__ bias4) {
    constexpr int G = D / 4;           // lanes per node
    const int per = 256 / G;           // nodes per block
    int node = blockIdx.x * per + threadIdx.x / G;
    int lane = threadIdx.x % G;
    if (node >= n) return;
    int2 be = rowBE[node];
    int j = be.x, end = be.y;
    float4 acc = make_float4(0.f, 0.f, 0.f, 0.f);
    for (; j + 7 < end; j += 8) {
        int2 e[8];
        float4 v[8];
#pragma unroll
        for (int q = 0; q < 8; q++) e[q] = edges[j + q];
#pragma unroll
        for (int q = 0; q < 8; q++) v[q] = h4[(size_t)e[q].x * G + lane];
#pragma unroll
        for (int q = 0; q < 8; q++) {
            float wq = __int_as_float(e[q].y);
            acc.x += v[q].x * wq;
            acc.y += v[q].y * wq;
            acc.z += v[q].z * wq;
            acc.w += v[q].w * wq;
        }
    }
    if (j + 3 < end) {
        int2 e0 = edges[j];
        int2 e1 = edges[j + 1];
        int2 e2 = edges[j + 2];
        int2 e3 = edges[j + 3];
        float4 v0 = h4[(size_t)e0.x * G + lane];
        float4 v1 = h4[(size_t)e1.x * G + lane];
        float4 v2 = h4[(size_t)e2.x * G + lane];
        float4 v3 = h4[(size_t)e3.x * G + lane];
        float w0 = __int_as_float(e0.y), w1 = __int_as_float(e1.y);
        float w2 = __int_as_float(e2.y), w3 = __int_as_float(e3.y);
        acc.x += v0.x * w0 + v1.x * w1 + v2.x * w2 + v3.x * w3;
        acc.y += v0.y * w0 + v1.y * w1 + v2.y * w2 + v3.y * w3;
        acc.z += v0.z * w0 + v1.z * w1 + v2.z * w2 + v3.z * w3;
        acc.w += v0.w * w0 + v1.w * w1 + v2.w * w2 + v3.w * w3;
        j += 4;
    }
    for (; j < end; j++) {
        int2 e = edges[j];
        float4 v = h4[(size_t)e.x * G + lane];
        float w0 = __int_as_float(e.y);
        acc.x += v.x * w0; acc.y += v.y * w0; acc.z += v.z * w0; acc.w += v.w * w0;
    }
    if (EPI) {
        float s = norm[node];
        float4 b = bias4[lane];
        acc.x = fmaxf(acc.x * s + b.x, 0.f);
        acc.y = fmaxf(acc.y * s + b.y, 0.f);
        acc.z = fmaxf(acc.z * s + b.z, 0.f);
        acc.w = fmaxf(acc.w * s + b.w, 0.f);
    }
    out4[(size_t)node * G + lane] = acc;
}

// agg3 + W4 fused (D=32): h3 = relu(agg(t3)*norm+b3) in regs (never stored),
// t4[node] = h3 @ W4 via per-lane partials + 8-lane __shfl_xor reduce.
__global__ __launch_bounds__(256) void k_aggw4(const float4* __restrict__ h4,
                        const int2* __restrict__ edges, const int2* __restrict__ rowBE,
                        const float* __restrict__ norm, const float4* __restrict__ b3_4,
                        const float* __restrict__ W4, int n, float4* __restrict__ t4) {
    __shared__ float w[128];
    if (threadIdx.x < 128) w[threadIdx.x] = W4[threadIdx.x];
    __syncthreads();
    int node = blockIdx.x * 32 + threadIdx.x / 8;
    int lane = threadIdx.x % 8;
    if (node >= n) return;
    float4 wr0 = ((const float4*)w)[4 * lane + 0];
    float4 wr1 = ((const float4*)w)[4 * lane + 1];
    float4 wr2 = ((const float4*)w)[4 * lane + 2];
    float4 wr3 = ((const float4*)w)[4 * lane + 3];
    int2 be = rowBE[node];
    int j = be.x, end = be.y;
    float4 acc = make_float4(0.f, 0.f, 0.f, 0.f);
    for (; j + 3 < end; j += 4) {
        int2 e0 = edges[j];
        int2 e1 = edges[j + 1];
        int2 e2 = edges[j + 2];
        int2 e3 = edges[j + 3];
        float4 v0 = h4[(size_t)e0.x * 8 + lane];
        float4 v1 = h4[(size_t)e1.x * 8 + lane];
        float4 v2 = h4[(size_t)e2.x * 8 + lane];
        float4 v3 = h4[(size_t)e3.x * 8 + lane];
        float w0 = __int_as_float(e0.y), w1 = __int_as_float(e1.y);
        float w2 = __int_as_float(e2.y), w3 = __int_as_float(e3.y);
        acc.x += v0.x * w0 + v1.x * w1 + v2.x * w2 + v3.x * w3;
        acc.y += v0.y * w0 + v1.y * w1 + v2.y * w2 + v3.y * w3;
        acc.z += v0.z * w0 + v1.z * w1 + v2.z * w2 + v3.z * w3;
        acc.w += v0.w * w0 + v1.w * w1 + v2.w * w2 + v3.w * w3;
    }
    for (; j < end; j++) {
        int2 e = edges[j];
        float4 v = h4[(size_t)e.x * 8 + lane];
        float w0 = __int_as_float(e.y);
        acc.x += v.x * w0; acc.y += v.y * w0; acc.z += v.z * w0; acc.w += v.w * w0;
    }
    float s = norm[node];
    float4 b = b3_4[lane];
    float hx = fmaxf(acc.x * s + b.x, 0.f);
    float hy = fmaxf(acc.y * s + b.y, 0.f);
    float hz = fmaxf(acc.z * s + b.z, 0.f);
    float hw = fmaxf(acc.w * s + b.w, 0.f);
    float4 p;
    p.x = hx * wr0.x + hy * wr1.x + hz * wr2.x + hw * wr3.x;
    p.y = hx * wr0.y + hy * wr1.y + hz * wr2.y + hw * wr3.y;
    p.z = hx * wr0.z + hy * wr1.z + hz * wr2.z + hw * wr3.z;
    p.w = hx * wr0.w + hy * wr1.w + hz * wr2.w + hw * wr3.w;
#pragma unroll
    for (int m = 1; m < 8; m <<= 1) {
        p.x += __shfl_xor(p.x, m);
        p.y += __shfl_xor(p.y, m);
        p.z += __shfl_xor(p.z, m);
        p.w += __shfl_xor(p.w, m);
    }
    if (lane == 0) t4[node] = p;
}

// out[N x M] = op(A[N x K] (opt row-scaled)) @ W[K x M] (+bias, relu).
// 4x4 microtile. A staged UNTRANSPOSED: Alds[k4*AP + r] = float4 of 4 k-vals
// for row r. AP = ROWS+1 (AP%8==1): staging b128 write touches each bank
// exactly 2x per quarter-wave (free). Inner: 4 broadcast a-reads + 4 dense
// w-reads (proven conflict-free patterns).
template <int K, int M, bool PRESCALE, bool BIAS_RELU>
__global__ __launch_bounds__(256) void k_gemm(const float* __restrict__ A,
                                              const float* __restrict__ W,
                                              const float* __restrict__ bias,
                                              const float* __restrict__ norm, int N,
                                              float* __restrict__ out) {
    constexpr int CT   = M / 4;        // col threads
    constexpr int RTH  = 256 / CT;     // row threads
    constexpr int ROWS = RTH * 4;      // rows per block
    constexpr int KC   = (K > 64) ? 64 : K;
    constexpr int K4   = KC / 4;
    constexpr int AP   = ROWS + 1;     // float4 slots per k-quad; ROWS%32==0 -> AP%8==1
    __shared__ float4 Alds[K4 * AP];
    __shared__ float  Wlds[KC * M];
    int t  = threadIdx.x;
    int tx = t % CT;
    int ty = t / CT;
    int row0 = blockIdx.x * ROWS;
    float acc[4][4] = {};
    for (int kc = 0; kc < K; kc += KC) {
        for (int idx = t; idx < KC * M / 4; idx += 256)
            ((float4*)Wlds)[idx] = ((const float4*)(W + kc * M))[idx];
        constexpr int A4 = ROWS * K4;
        for (int idx = t; idx < A4; idx += 256) {
            int r  = idx / K4;
            int k4 = idx % K4;
            int grow = row0 + r;
            float4 v = make_float4(0.f, 0.f, 0.f, 0.f);
            if (grow < N) {
                v = *(const float4*)(A + (size_t)grow * K + kc + k4 * 4);
                if (PRESCALE) {
                    float s = norm[grow];
                    v.x *= s; v.y *= s; v.z *= s; v.w *= s;
                }
            }
            Alds[k4 * AP + r] = v;
        }
        __syncthreads();
#pragma unroll 2
        for (int k4 = 0; k4 < K4; k4++) {
            float4 a0 = Alds[k4 * AP + ty * 4 + 0];
            float4 a1 = Alds[k4 * AP + ty * 4 + 1];
            float4 a2 = Alds[k4 * AP + ty * 4 + 2];
            float4 a3 = Alds[k4 * AP + ty * 4 + 3];
            const float* wb = &Wlds[(k4 * 4) * M + tx * 4];
            float4 w0 = *(const float4*)(wb);
            float4 w1 = *(const float4*)(wb + M);
            float4 w2 = *(const float4*)(wb + 2 * M);
            float4 w3 = *(const float4*)(wb + 3 * M);
#define GSTEP(AK, WV) \
            acc[0][0] += a0.AK * WV.x; acc[0][1] += a0.AK * WV.y; acc[0][2] += a0.AK * WV.z; acc[0][3] += a0.AK * WV.w; \
            acc[1][0] += a1.AK * WV.x; acc[1][1] += a1.AK * WV.y; acc[1][2] += a1.AK * WV.z; acc[1][3] += a1.AK * WV.w; \
            acc[2][0] += a2.AK * WV.x; acc[2][1] += a2.AK * WV.y; acc[2][2] += a2.AK * WV.z; acc[2][3] += a2.AK * WV.w; \
            acc[3][0] += a3.AK * WV.x; acc[3][1] += a3.AK * WV.y; acc[3][2] += a3.AK * WV.z; acc[3][3] += a3.AK * WV.w;
            GSTEP(x, w0)
            GSTEP(y, w1)
            GSTEP(z, w2)
            GSTEP(w, w3)
#undef GSTEP
        }
        __syncthreads();
    }
#pragma unroll
    for (int i = 0; i < 4; i++) {
        int grow = row0 + ty * 4 + i;
        if (grow < N) {
            float4 o = make_float4(acc[i][0], acc[i][1], acc[i][2], acc[i][3]);
            if (BIAS_RELU) {
                float4 b = *(const float4*)(bias + tx * 4);
                o.x = fmaxf(o.x + b.x, 0.f);
                o.y = fmaxf(o.y + b.y, 0.f);
                o.z = fmaxf(o.z + b.z, 0.f);
                o.w = fmaxf(o.w + b.w, 0.f);
            }
            *(float4*)(out + (size_t)grow * M + tx * 4) = o;
        }
    }
}

// L4 fused: per node (1 thread): acc = sum_e t4[src_e]*norm_out_e ;
// v = acc*norm_in + b4 ; wave segmented-scan pool on sorted gid -> atomics
__global__ __launch_bounds__(256) void k_aggpool(const float4* __restrict__ t4,
                        const int2* __restrict__ edges, const int2* __restrict__ rowBE,
                        const float* __restrict__ norm, const float* __restrict__ b4,
                        const int* __restrict__ gid, int N,
                        float* __restrict__ sums, float* __restrict__ counts) {
    int n = blockIdx.x * blockDim.x + threadIdx.x;
    int lane = threadIdx.x & 63;
    bool valid = (n < N);
    float v0 = 0.f, v1 = 0.f, v2 = 0.f, v3 = 0.f, cnt = 0.f;
    int g = -1;
    if (valid) {
        g = gid[n];
        int2 be = rowBE[n];
        int j = be.x, end = be.y;
        float4 acc = make_float4(0.f, 0.f, 0.f, 0.f);
        for (; j + 3 < end; j += 4) {
            int2 e0 = edges[j];
            int2 e1 = edges[j + 1];
            int2 e2 = edges[j + 2];
            int2 e3 = edges[j + 3];
            float4 x0 = t4[e0.x];
            float4 x1 = t4[e1.x];
            float4 x2 = t4[e2.x];
            float4 x3 = t4[e3.x];
            float w0 = __int_as_float(e0.y), w1 = __int_as_float(e1.y);
            float w2 = __int_as_float(e2.y), w3 = __int_as_float(e3.y);
            acc.x += x0.x * w0 + x1.x * w1 + x2.x * w2 + x3.x * w3;
            acc.y += x0.y * w0 + x1.y * w1 + x2.y * w2 + x3.y * w3;
            acc.z += x0.z * w0 + x1.z * w1 + x2.z * w2 + x3.z * w3;
            acc.w += x0.w * w0 + x1.w * w1 + x2.w * w2 + x3.w * w3;
        }
        for (; j < end; j++) {
            int2 e = edges[j];
            float4 x = t4[e.x];
            float w0 = __int_as_float(e.y);
            acc.x += x.x * w0; acc.y += x.y * w0; acc.z += x.z * w0; acc.w += x.w * w0;
        }
        float s = norm[n];
        v0 = acc.x * s + b4[0];
        v1 = acc.y * s + b4[1];
        v2 = acc.z * s + b4[2];
        v3 = acc.w * s + b4[3];
        cnt = 1.f;
    }
    // segmented inclusive scan across the 64-lane wave (gid sorted)
#pragma unroll
    for (int off = 1; off < 64; off <<= 1) {
        float u0 = __shfl_up(v0, off);
        float u1 = __shfl_up(v1, off);
        float u2 = __shfl_up(v2, off);
        float u3 = __shfl_up(v3, off);
        float uc = __shfl_up(cnt, off);
        int   ug = __shfl_up(g, off);
        if (lane >= off && ug == g) { v0 += u0; v1 += u1; v2 += u2; v3 += u3; cnt += uc; }
    }
    int gnext = __shfl_down(g, 1);
    bool boundary = (lane == 63) || (gnext != g);
    if (boundary && valid) {
        atomicAdd(&sums[g * 4 + 0], v0);
        atomicAdd(&sums[g * 4 + 1], v1);
        atomicAdd(&sums[g * 4 + 2], v2);
        atomicAdd(&sums[g * 4 + 3], v3);
        atomicAdd(&counts[g], cnt);
    }
}

__global__ void k_div(const float* __restrict__ sums, const float* __restrict__ counts,
                      int G, float* __restrict__ out) {
    int idx = blockIdx.x * blockDim.x + threadIdx.x;
    if (idx >= G * 4) return;
    out[idx] = sums[idx] / fmaxf(counts[idx >> 2], 1.0f);
}

extern "C" void kernel_launch(void* const* d_in, const int* in_sizes, int n_in,
                              void* d_out, int out_size, void* d_ws, size_t ws_size,
                              hipStream_t stream) {
    const float* x  = (const float*)d_in[0];
    const float* W1 = (const float*)d_in[1];
    const float* b1 = (const float*)d_in[2];
    const float* W2 = (const float*)d_in[3];
    const float* b2 = (const float*)d_in[4];
    const float* W3 = (const float*)d_in[5];
    const float* b3 = (const float*)d_in[6];
    const float* W4 = (const float*)d_in[7];
    const float* b4 = (const float*)d_in[8];
    const int* src = (const int*)d_in[9];
    const int* dst = (const int*)d_in[10];
    const int* gid = (const int*)d_in[11];

    const int N = in_sizes[0] / 64;
    const int E = in_sizes[9];
    const int G = out_size / 4;
    const int NP = ((N + 63) / 64) * 64;
    const int NBIN = (N + 511) >> 9;          // coarse bins (<=256 for N<=131072)
    const int T = (E + TILE - 1) / TILE;      // build tiles

    char* ws = (char*)d_ws;
    size_t off = 0;
    auto alloc = [&](size_t bytes) -> void* {
        void* p = (void*)(ws + off);
        off += (bytes + 255) & ~(size_t)255;
        return p;
    };
    // sums/counts/cntD/cntS contiguous (all sizes multiples of 256B) -> one memset
    float* sums     = (float*)alloc(2048 * 4);   // 500*4 used
    float* counts   = (float*)alloc(512 * 4);
    int*   cntD     = (int*)alloc(256 * 4);
    int*   cntS     = (int*)alloc(256 * 4);
    int*   bucketD  = (int*)alloc((size_t)NBIN * SLOT * 4);
    unsigned short* bucketS = (unsigned short*)alloc((size_t)NBIN * SLOT * 2);
    int2*  edges    = (int2*)alloc((size_t)NBIN * SLOT * 8);
    int2*  rowBE    = (int2*)alloc((size_t)NP * 8);
    float* norm_out = (float*)alloc((size_t)NP * 4);
    float* norm_in  = (float*)alloc((size_t)NP * 4);
    float* region0  = (float*)alloc((size_t)N * 128 * 4);  // h1
    float* region1  = (float*)alloc((size_t)N * 64 * 4);   // agg1 / t2 / t3
    float* region2  = (float*)alloc((size_t)N * 64 * 4);   // h2 / t4

    hipMemsetAsync(sums, 0, (2048 + 512 + 256 + 256) * 4, stream);

    // ---- slotted atomic-light CSR build (3 kernels) ----
    k_buildbins<<<T, 256, 0, stream>>>(src, dst, E, NBIN, cntD, cntS, bucketD, bucketS);
    k_degout<<<NBIN, 256, 0, stream>>>(bucketS, cntS, N, norm_out);
    k_build<<<NBIN, 256, 0, stream>>>(bucketD, cntD, norm_out, N, rowBE, norm_in, edges);

    int nb = (N + 255) / 256;
    // L1: agg(x) -> region1 ; h1 = relu((agg*norm_in)@W1+b1) -> region0
    k_agg<64, false><<<(N + 15) / 16, 256, 0, stream>>>((const float4*)x, edges, rowBE, N,
                                                        (float4*)region1, nullptr, nullptr);
    k_gemm<64, 128, true, true><<<(N + 31) / 32, 256, 0, stream>>>(region1, W1, b1, norm_in, N, region0);
    // L2: t2 = h1@W2 -> region1 ; h2 = relu(agg(t2)*norm+b2) -> region2 (fused epi)
    k_gemm<128, 64, false, false><<<(N + 63) / 64, 256, 0, stream>>>(region0, W2, nullptr, nullptr, N, region1);
    k_agg<64, true><<<(N + 15) / 16, 256, 0, stream>>>((const float4*)region1, edges, rowBE, N,
                                                       (float4*)region2, norm_in, (const float4*)b2);
    // L3: t3 = h2@W3 -> region1 ; t4 = relu(agg(t3)*norm+b3)@W4 -> region2 (h3 never stored)
    k_gemm<64, 32, false, false><<<(N + 127) / 128, 256, 0, stream>>>(region2, W3, nullptr, nullptr, N, region1);
    k_aggw4<<<(N + 31) / 32, 256, 0, stream>>>((const float4*)region1, edges, rowBE,
                                               norm_in, (const float4*)b3, W4, N,
                                               (float4*)region2);
    // L4: fused gather(t4)+norm+bias+pool
    k_aggpool<<<nb, 256, 0, stream>>>((const float4*)region2, edges, rowBE,
                                      norm_in, b4, gid, N, sums, counts);
    k_div<<<(G * 4 + 255) / 256, 256, 0, stream>>>(sums, counts, G, (float*)d_out);
}

// Round 12
// 279.934 us; speedup vs baseline: 1.1005x; 1.0986x over previous
//
#include <hip/hip_runtime.h>
#include <hip/hip_bf16.h>

// ---------------------------------------------------------------------------
// GCN 4-layer forward on MI355X.
//   - R6: single-pass SLOTTED CSR build (one device atomic per (bin,tile)).
//   - R5/R7: float4 gathers, 8-edge unroll.
//   - R10/R11: LDS bank law: dense float4 @16B*tid stride and stride AP%8==1
//     staging are free; transposed scalar staging (stride==4 mod 32) is 8-way.
//   - R12: MEGA-FUSION. k_fused1 = agg(x)->*norm->@W1+b1+relu->@W2 per
//     32-row block (agg1 + h1 never hit HBM: ~153MB saved). k_fused2 =
//     agg(t2)+relu(norm+b2)->@W3 (h2 never hits HBM: ~51MB). 13 -> 8
//     dispatches. All LDS patterns are the proven conflict-free forms.
//   - k_aggw4: gather(t3)->h3 in regs ->@W4 (R6). Pool: wave segmented scan
//     on sorted gid (R1).
// ---------------------------------------------------------------------------

#define TILE 4096   // edges per build tile (256 threads x 16)
#define SLOT 8192   // per-bin slot capacity (bin = 512 nodes, mean ~4080 edges)

// --- build pass 1: tile->LDS, histogram, reserve slot space, scatter -------
__global__ __launch_bounds__(256) void k_buildbins(
        const int* __restrict__ src, const int* __restrict__ dst, int E, int NBIN,
        int* __restrict__ cntD, int* __restrict__ cntS,
        int* __restrict__ bucketD, unsigned short* __restrict__ bucketS) {
    __shared__ int ssrc[TILE];
    __shared__ int sdst[TILE];
    __shared__ int hD[256], hS[256], bD[256], bS[256];
    int t = threadIdx.x;
    hD[t] = 0; hS[t] = 0;
    __syncthreads();
    int base = blockIdx.x * TILE;
    int lim = min(TILE, E - base);
#pragma unroll
    for (int k = 0; k < TILE / 256; k++) {
        int i = k * 256 + t;
        if (i < lim) {
            int d = dst[base + i], sv = src[base + i];
            sdst[i] = d; ssrc[i] = sv;
            atomicAdd(&hD[d >> 9], 1);
            atomicAdd(&hS[sv >> 9], 1);
        }
    }
    __syncthreads();
    if (t < NBIN) {
        bD[t] = (hD[t] > 0) ? atomicAdd(&cntD[t], hD[t]) : 0;
        bS[t] = (hS[t] > 0) ? atomicAdd(&cntS[t], hS[t]) : 0;
        hD[t] = 0; hS[t] = 0;
    }
    __syncthreads();
#pragma unroll
    for (int k = 0; k < TILE / 256; k++) {
        int i = k * 256 + t;
        if (i < lim) {
            int d = sdst[i], sv = ssrc[i];
            int binD = d >> 9, binS = sv >> 9;
            int pD = atomicAdd(&hD[binD], 1) + bD[binD];
            bucketD[binD * SLOT + pD] = (sv << 9) | (d & 511);
            int pS = atomicAdd(&hS[binS], 1) + bS[binS];
            bucketS[binS * SLOT + pS] = (unsigned short)(sv & 511);
        }
    }
}

// --- build pass 2: per-src-bucket LDS count -> norm_out --------------------
__global__ __launch_bounds__(256) void k_degout(const unsigned short* __restrict__ bucketS,
                                                const int* __restrict__ cntS,
                                                int N, float* __restrict__ norm_out) {
    __shared__ int cnt[512];
    int t = threadIdx.x;
    cnt[t] = 0; cnt[t + 256] = 0;
    __syncthreads();
    int bin = blockIdx.x;
    int b0 = bin * SLOT, cn = cntS[bin];
    for (int j = t; j < cn; j += 256) atomicAdd(&cnt[bucketS[b0 + j]], 1);
    __syncthreads();
    int base = bin << 9;
    for (int l = t; l < 512; l += 256) {
        int g = base + l;
        if (g < N) norm_out[g] = rsqrtf(fmaxf((float)cnt[l], 1.0f));
    }
}

// --- build pass 3: per-dst-bucket count+scan -> rowBE/norm_in, place edges -
__global__ __launch_bounds__(256) void k_build(const int* __restrict__ bucketD,
                                               const int* __restrict__ cntDg,
                                               const float* __restrict__ norm_out,
                                               int N, int2* __restrict__ rowBE,
                                               float* __restrict__ norm_in,
                                               int2* __restrict__ edges) {
    __shared__ int cnt[512], sc[512];
    int t = threadIdx.x;
    cnt[t] = 0; cnt[t + 256] = 0;
    __syncthreads();
    int bin = blockIdx.x;
    int b0 = bin * SLOT, cn = cntDg[bin];
    for (int j = t; j < cn; j += 256) atomicAdd(&cnt[bucketD[b0 + j] & 511], 1);
    __syncthreads();
    sc[t] = cnt[t]; sc[t + 256] = cnt[t + 256];
    __syncthreads();
    for (int off = 1; off < 512; off <<= 1) {
        int v0 = (t >= off) ? sc[t - off] : 0;
        int i1 = t + 256;
        int v1 = sc[i1 - off];   // i1 >= 256 >= off always
        __syncthreads();
        sc[t] += v0; sc[i1] += v1;
        __syncthreads();
    }
    int base = bin << 9;
    for (int l = t; l < 512; l += 256) {
        int g = base + l;
        int e = sc[l] - cnt[l];          // exclusive within bucket
        if (g < N) {
            rowBE[g] = make_int2(b0 + e, b0 + sc[l]);
            norm_in[g] = rsqrtf(fmaxf((float)cnt[l], 1.0f));
        }
        cnt[l] = e;                      // becomes placement cursor
    }
    __syncthreads();
    for (int j = t; j < cn; j += 256) {
        int p = bucketD[b0 + j];
        int sv = p >> 9, dl = p & 511;
        int pos = atomicAdd(&cnt[dl], 1);
        edges[b0 + pos] = make_int2(sv, __float_as_int(norm_out[sv]));
    }
}

// shared gather primitive: sum_e w_e * h4[src_e*G + lane], 8-edge unroll
template <int G>
__device__ __forceinline__ float4 gather_row(const float4* __restrict__ h4,
                                             const int2* __restrict__ edges,
                                             int j, int end, int lane) {
    float4 acc = make_float4(0.f, 0.f, 0.f, 0.f);
    for (; j + 7 < end; j += 8) {
        int2 e[8];
        float4 v[8];
#pragma unroll
        for (int q = 0; q < 8; q++) e[q] = edges[j + q];
#pragma unroll
        for (int q = 0; q < 8; q++) v[q] = h4[(size_t)e[q].x * G + lane];
#pragma unroll
        for (int q = 0; q < 8; q++) {
            float wq = __int_as_float(e[q].y);
            acc.x += v[q].x * wq; acc.y += v[q].y * wq;
            acc.z += v[q].z * wq; acc.w += v[q].w * wq;
        }
    }
    if (j + 3 < end) {
        int2 e0 = edges[j], e1 = edges[j + 1], e2 = edges[j + 2], e3 = edges[j + 3];
        float4 v0 = h4[(size_t)e0.x * G + lane];
        float4 v1 = h4[(size_t)e1.x * G + lane];
        float4 v2 = h4[(size_t)e2.x * G + lane];
        float4 v3 = h4[(size_t)e3.x * G + lane];
        float w0 = __int_as_float(e0.y), w1 = __int_as_float(e1.y);
        float w2 = __int_as_float(e2.y), w3 = __int_as_float(e3.y);
        acc.x += v0.x * w0 + v1.x * w1 + v2.x * w2 + v3.x * w3;
        acc.y += v0.y * w0 + v1.y * w1 + v2.y * w2 + v3.y * w3;
        acc.z += v0.z * w0 + v1.z * w1 + v2.z * w2 + v3.z * w3;
        acc.w += v0.w * w0 + v1.w * w1 + v2.w * w2 + v3.w * w3;
        j += 4;
    }
    for (; j < end; j++) {
        int2 e = edges[j];
        float4 v = h4[(size_t)e.x * G + lane];
        float w0 = __int_as_float(e.y);
        acc.x += v.x * w0; acc.y += v.y * w0; acc.z += v.z * w0; acc.w += v.w * w0;
    }
    return acc;
}

// --- L1+L2 fused: per 32-row block:
//   A = agg(x)*norm_in  (gather -> LDS, never global)
//   H = relu(A@W1 + b1) (regs -> LDS, never global)
//   t2 = H@W2           (-> global)
__global__ __launch_bounds__(256) void k_fused1(const float4* __restrict__ x4,
                        const int2* __restrict__ edges, const int2* __restrict__ rowBE,
                        const float* __restrict__ norm, const float* __restrict__ W1,
                        const float* __restrict__ b1, const float* __restrict__ W2,
                        int N, float* __restrict__ t2) {
    constexpr int AP = 33;                 // float4 slots per k4; AP%8==1 -> free staging
    __shared__ float4 Alds[32 * AP];       // phase1: [k4<16][r<32] ; phase2: [k4<32][r<32]
    __shared__ float  Wlds[64 * 128];      // W1 (64x128), then W2 (128x64) — same size
    int t = threadIdx.x;
    int row0 = blockIdx.x * 32;
    // gather phase: 2 passes x (16 nodes x 16 float4-lanes)
#pragma unroll
    for (int pass = 0; pass < 2; pass++) {
        int r = pass * 16 + (t >> 4);
        int lane = t & 15;
        int node = row0 + r;
        float4 acc = make_float4(0.f, 0.f, 0.f, 0.f);
        if (node < N) {
            int2 be = rowBE[node];
            acc = gather_row<16>(x4, edges, be.x, be.y, lane);
            float s = norm[node];
            acc.x *= s; acc.y *= s; acc.z *= s; acc.w *= s;
        }
        Alds[lane * AP + r] = acc;
    }
    for (int idx = t; idx < 64 * 128 / 4; idx += 256)
        ((float4*)Wlds)[idx] = ((const float4*)W1)[idx];
    __syncthreads();
    // GEMM1: 32x64 @ 64x128, 4x4/thread (tx<32, ty<8)
    int tx = t & 31, ty = t >> 5;
    float acc1[4][4] = {};
#pragma unroll 2
    for (int k4 = 0; k4 < 16; k4++) {
        float4 a0 = Alds[k4 * AP + ty * 4 + 0];
        float4 a1 = Alds[k4 * AP + ty * 4 + 1];
        float4 a2 = Alds[k4 * AP + ty * 4 + 2];
        float4 a3 = Alds[k4 * AP + ty * 4 + 3];
        const float* wb = &Wlds[(k4 * 4) * 128 + tx * 4];
        float4 w0 = *(const float4*)(wb);
        float4 w1 = *(const float4*)(wb + 128);
        float4 w2 = *(const float4*)(wb + 256);
        float4 w3 = *(const float4*)(wb + 384);
#define GSTEP(AK, WV) \
        acc1[0][0] += a0.AK * WV.x; acc1[0][1] += a0.AK * WV.y; acc1[0][2] += a0.AK * WV.z; acc1[0][3] += a0.AK * WV.w; \
        acc1[1][0] += a1.AK * WV.x; acc1[1][1] += a1.AK * WV.y; acc1[1][2] += a1.AK * WV.z; acc1[1][3] += a1.AK * WV.w; \
        acc1[2][0] += a2.AK * WV.x; acc1[2][1] += a2.AK * WV.y; acc1[2][2] += a2.AK * WV.z; acc1[2][3] += a2.AK * WV.w; \
        acc1[3][0] += a3.AK * WV.x; acc1[3][1] += a3.AK * WV.y; acc1[3][2] += a3.AK * WV.z; acc1[3][3] += a3.AK * WV.w;
        GSTEP(x, w0) GSTEP(y, w1) GSTEP(z, w2) GSTEP(w, w3)
    }
    float4 bb = *(const float4*)(b1 + tx * 4);
    float4 h[4];
#pragma unroll
    for (int i = 0; i < 4; i++) {
        h[i].x = fmaxf(acc1[i][0] + bb.x, 0.f);
        h[i].y = fmaxf(acc1[i][1] + bb.y, 0.f);
        h[i].z = fmaxf(acc1[i][2] + bb.z, 0.f);
        h[i].w = fmaxf(acc1[i][3] + bb.w, 0.f);
    }
    __syncthreads();           // GEMM1 LDS reads done -> safe to overwrite
#pragma unroll
    for (int i = 0; i < 4; i++) Alds[tx * AP + ty * 4 + i] = h[i];   // H: [k4=tx][r]
    for (int idx = t; idx < 128 * 64 / 4; idx += 256)
        ((float4*)Wlds)[idx] = ((const float4*)W2)[idx];
    __syncthreads();
    // GEMM2: 32x128 @ 128x64, 2 rows x 4 cols/thread (tx2<16, ty2<16)
    int tx2 = t & 15, ty2 = t >> 4;
    float acc2[2][4] = {};
#pragma unroll 2
    for (int k4 = 0; k4 < 32; k4++) {
        float4 a0 = Alds[k4 * AP + ty2 * 2 + 0];
        float4 a1 = Alds[k4 * AP + ty2 * 2 + 1];
        const float* wb = &Wlds[(k4 * 4) * 64 + tx2 * 4];
        float4 w0 = *(const float4*)(wb);
        float4 w1 = *(const float4*)(wb + 64);
        float4 w2 = *(const float4*)(wb + 128);
        float4 w3 = *(const float4*)(wb + 192);
#define GSTEP2(AK, WV) \
        acc2[0][0] += a0.AK * WV.x; acc2[0][1] += a0.AK * WV.y; acc2[0][2] += a0.AK * WV.z; acc2[0][3] += a0.AK * WV.w; \
        acc2[1][0] += a1.AK * WV.x; acc2[1][1] += a1.AK * WV.y; acc2[1][2] += a1.AK * WV.z; acc2[1][3] += a1.AK * WV.w;
        GSTEP2(x, w0) GSTEP2(y, w1) GSTEP2(z, w2) GSTEP2(w, w3)
#undef GSTEP2
    }
#pragma unroll
    for (int i = 0; i < 2; i++) {
        int grow = row0 + ty2 * 2 + i;
        if (grow < N) {
            float4 o = make_float4(acc2[i][0], acc2[i][1], acc2[i][2], acc2[i][3]);
            *(float4*)(t2 + (size_t)grow * 64 + tx2 * 4) = o;
        }
    }
#undef GSTEP
}

// --- L2-agg + L3 fused: per 32-row block:
//   H2 = relu(agg(t2)*norm + b2)  (gather -> LDS, never global)
//   t3 = H2@W3                    (-> global)
__global__ __launch_bounds__(256) void k_fused2(const float4* __restrict__ t2_4,
                        const int2* __restrict__ edges, const int2* __restrict__ rowBE,
                        const float* __restrict__ norm, const float* __restrict__ b2,
                        const float* __restrict__ W3, int N, float* __restrict__ t3) {
    constexpr int AP = 33;
    __shared__ float4 Alds[16 * AP];       // [k4<16][r<32]
    __shared__ float  Wlds[64 * 32];       // W3
    int t = threadIdx.x;
    int row0 = blockIdx.x * 32;
#pragma unroll
    for (int pass = 0; pass < 2; pass++) {
        int r = pass * 16 + (t >> 4);
        int lane = t & 15;
        int node = row0 + r;
        float4 acc = make_float4(0.f, 0.f, 0.f, 0.f);
        if (node < N) {
            int2 be = rowBE[node];
            acc = gather_row<16>(t2_4, edges, be.x, be.y, lane);
            float s = norm[node];
            float4 b = ((const float4*)b2)[lane];
            acc.x = fmaxf(acc.x * s + b.x, 0.f);
            acc.y = fmaxf(acc.y * s + b.y, 0.f);
            acc.z = fmaxf(acc.z * s + b.z, 0.f);
            acc.w = fmaxf(acc.w * s + b.w, 0.f);
        }
        Alds[lane * AP + r] = acc;
    }
    for (int idx = t; idx < 64 * 32 / 4; idx += 256)
        ((float4*)Wlds)[idx] = ((const float4*)W3)[idx];
    __syncthreads();
    // GEMM3: 32x64 @ 64x32, 1 row x 4 cols/thread (tx<8, ty<32)
    int tx = t & 7, ty = t >> 3;
    float a0c = 0.f;
    float acc3[4] = {};
#pragma unroll 2
    for (int k4 = 0; k4 < 16; k4++) {
        float4 a = Alds[k4 * AP + ty];
        const float* wb = &Wlds[(k4 * 4) * 32 + tx * 4];
        float4 w0 = *(const float4*)(wb);
        float4 w1 = *(const float4*)(wb + 32);
        float4 w2 = *(const float4*)(wb + 64);
        float4 w3 = *(const float4*)(wb + 96);
        acc3[0] += a.x * w0.x + a.y * w1.x + a.z * w2.x + a.w * w3.x;
        acc3[1] += a.x * w0.y + a.y * w1.y + a.z * w2.y + a.w * w3.y;
        acc3[2] += a.x * w0.z + a.y * w1.z + a.z * w2.z + a.w * w3.z;
        acc3[3] += a.x * w0.w + a.y * w1.w + a.z * w2.w + a.w * w3.w;
    }
    (void)a0c;
    int grow = row0 + ty;
    if (grow < N) {
        float4 o = make_float4(acc3[0], acc3[1], acc3[2], acc3[3]);
        *(float4*)(t3 + (size_t)grow * 32 + tx * 4) = o;
    }
}

// agg3 + W4 fused (D=32): h3 = relu(agg(t3)*norm+b3) in regs (never stored),
// t4[node] = h3 @ W4 via per-lane partials + 8-lane __shfl_xor reduce.
__global__ __launch_bounds__(256) void k_aggw4(const float4* __restrict__ h4,
                        const int2* __restrict__ edges, const int2* __restrict__ rowBE,
                        const float* __restrict__ norm, const float4* __restrict__ b3_4,
                        const float* __restrict__ W4, int n, float4* __restrict__ t4) {
    __shared__ float w[128];
    if (threadIdx.x < 128) w[threadIdx.x] = W4[threadIdx.x];
    __syncthreads();
    int node = blockIdx.x * 32 + threadIdx.x / 8;
    int lane = threadIdx.x % 8;
    if (node >= n) return;
    float4 wr0 = ((const float4*)w)[4 * lane + 0];
    float4 wr1 = ((const float4*)w)[4 * lane + 1];
    float4 wr2 = ((const float4*)w)[4 * lane + 2];
    float4 wr3 = ((const float4*)w)[4 * lane + 3];
    int2 be = rowBE[node];
    float4 acc = gather_row<8>(h4, edges, be.x, be.y, lane);
    float s = norm[node];
    float4 b = b3_4[lane];
    float hx = fmaxf(acc.x * s + b.x, 0.f);
    float hy = fmaxf(acc.y * s + b.y, 0.f);
    float hz = fmaxf(acc.z * s + b.z, 0.f);
    float hw = fmaxf(acc.w * s + b.w, 0.f);
    float4 p;
    p.x = hx * wr0.x + hy * wr1.x + hz * wr2.x + hw * wr3.x;
    p.y = hx * wr0.y + hy * wr1.y + hz * wr2.y + hw * wr3.y;
    p.z = hx * wr0.z + hy * wr1.z + hz * wr2.z + hw * wr3.z;
    p.w = hx * wr0.w + hy * wr1.w + hz * wr2.w + hw * wr3.w;
#pragma unroll
    for (int m = 1; m < 8; m <<= 1) {
        p.x += __shfl_xor(p.x, m);
        p.y += __shfl_xor(p.y, m);
        p.z += __shfl_xor(p.z, m);
        p.w += __shfl_xor(p.w, m);
    }
    if (lane == 0) t4[node] = p;
}

// L4 fused: per node (1 thread): acc = sum_e t4[src_e]*w_e ; v = acc*norm+b4 ;
// wave segmented-scan pool on sorted gid -> atomics
__global__ __launch_bounds__(256) void k_aggpool(const float4* __restrict__ t4,
                        const int2* __restrict__ edges, const int2* __restrict__ rowBE,
                        const float* __restrict__ norm, const float* __restrict__ b4,
                        const int* __restrict__ gid, int N,
                        float* __restrict__ sums, float* __restrict__ counts) {
    int n = blockIdx.x * blockDim.x + threadIdx.x;
    int lane = threadIdx.x & 63;
    bool valid = (n < N);
    float v0 = 0.f, v1 = 0.f, v2 = 0.f, v3 = 0.f, cnt = 0.f;
    int g = -1;
    if (valid) {
        g = gid[n];
        int2 be = rowBE[n];
        float4 acc = gather_row<1>(t4, edges, be.x, be.y, 0);
        float s = norm[n];
        v0 = acc.x * s + b4[0];
        v1 = acc.y * s + b4[1];
        v2 = acc.z * s + b4[2];
        v3 = acc.w * s + b4[3];
        cnt = 1.f;
    }
#pragma unroll
    for (int off = 1; off < 64; off <<= 1) {
        float u0 = __shfl_up(v0, off);
        float u1 = __shfl_up(v1, off);
        float u2 = __shfl_up(v2, off);
        float u3 = __shfl_up(v3, off);
        float uc = __shfl_up(cnt, off);
        int   ug = __shfl_up(g, off);
        if (lane >= off && ug == g) { v0 += u0; v1 += u1; v2 += u2; v3 += u3; cnt += uc; }
    }
    int gnext = __shfl_down(g, 1);
    bool boundary = (lane == 63) || (gnext != g);
    if (boundary && valid) {
        atomicAdd(&sums[g * 4 + 0], v0);
        atomicAdd(&sums[g * 4 + 1], v1);
        atomicAdd(&sums[g * 4 + 2], v2);
        atomicAdd(&sums[g * 4 + 3], v3);
        atomicAdd(&counts[g], cnt);
    }
}

__global__ void k_div(const float* __restrict__ sums, const float* __restrict__ counts,
                      int G, float* __restrict__ out) {
    int idx = blockIdx.x * blockDim.x + threadIdx.x;
    if (idx >= G * 4) return;
    out[idx] = sums[idx] / fmaxf(counts[idx >> 2], 1.0f);
}

extern "C" void kernel_launch(void* const* d_in, const int* in_sizes, int n_in,
                              void* d_out, int out_size, void* d_ws, size_t ws_size,
                              hipStream_t stream) {
    const float* x  = (const float*)d_in[0];
    const float* W1 = (const float*)d_in[1];
    const float* b1 = (const float*)d_in[2];
    const float* W2 = (const float*)d_in[3];
    const float* b2 = (const float*)d_in[4];
    const float* W3 = (const float*)d_in[5];
    const float* b3 = (const float*)d_in[6];
    const float* W4 = (const float*)d_in[7];
    const float* b4 = (const float*)d_in[8];
    const int* src = (const int*)d_in[9];
    const int* dst = (const int*)d_in[10];
    const int* gid = (const int*)d_in[11];

    const int N = in_sizes[0] / 64;
    const int E = in_sizes[9];
    const int G = out_size / 4;
    const int NP = ((N + 63) / 64) * 64;
    const int NBIN = (N + 511) >> 9;          // coarse bins (<=256 for N<=131072)
    const int T = (E + TILE - 1) / TILE;      // build tiles

    char* ws = (char*)d_ws;
    size_t off = 0;
    auto alloc = [&](size_t bytes) -> void* {
        void* p = (void*)(ws + off);
        off += (bytes + 255) & ~(size_t)255;
        return p;
    };
    float* sums     = (float*)alloc(2048 * 4);   // 500*4 used
    float* counts   = (float*)alloc(512 * 4);
    int*   cntD     = (int*)alloc(256 * 4);
    int*   cntS     = (int*)alloc(256 * 4);
    int*   bucketD  = (int*)alloc((size_t)NBIN * SLOT * 4);
    unsigned short* bucketS = (unsigned short*)alloc((size_t)NBIN * SLOT * 2);
    int2*  edges    = (int2*)alloc((size_t)NBIN * SLOT * 8);
    int2*  rowBE    = (int2*)alloc((size_t)NP * 8);
    float* norm_out = (float*)alloc((size_t)NP * 4);
    float* norm_in  = (float*)alloc((size_t)NP * 4);
    float* t2buf    = (float*)alloc((size_t)N * 64 * 4);
    float* t3buf    = (float*)alloc((size_t)N * 32 * 4);
    float* t4buf    = (float*)alloc((size_t)N * 4 * 4);

    hipMemsetAsync(sums, 0, (2048 + 512 + 256 + 256) * 4, stream);

    // ---- slotted atomic-light CSR build (3 kernels) ----
    k_buildbins<<<T, 256, 0, stream>>>(src, dst, E, NBIN, cntD, cntS, bucketD, bucketS);
    k_degout<<<NBIN, 256, 0, stream>>>(bucketS, cntS, N, norm_out);
    k_build<<<NBIN, 256, 0, stream>>>(bucketD, cntD, norm_out, N, rowBE, norm_in, edges);

    int fb = (N + 31) / 32;
    int nb = (N + 255) / 256;
    // L1+L2: t2 = relu(agg(x)*norm@W1+b1)@W2
    k_fused1<<<fb, 256, 0, stream>>>((const float4*)x, edges, rowBE, norm_in,
                                     W1, b1, W2, N, t2buf);
    // L2-agg+L3: t3 = relu(agg(t2)*norm+b2)@W3
    k_fused2<<<fb, 256, 0, stream>>>((const float4*)t2buf, edges, rowBE, norm_in,
                                     b2, W3, N, t3buf);
    // L3-agg+L4-W: t4 = relu(agg(t3)*norm+b3)@W4
    k_aggw4<<<fb, 256, 0, stream>>>((const float4*)t3buf, edges, rowBE,
                                    norm_in, (const float4*)b3, W4, N,
                                    (float4*)t4buf);
    // L4: fused gather(t4)+norm+bias+pool
    k_aggpool<<<nb, 256, 0, stream>>>((const float4*)t4buf, edges, rowBE,
                                      norm_in, b4, gid, N, sums, counts);
    k_div<<<(G * 4 + 255) / 256, 256, 0, stream>>>(sums, counts, G, (float*)d_out);
}